// Round 1
// baseline (811.166 us; speedup 1.0000x reference)
//
#include <hip/hip_runtime.h>
#include <math.h>

namespace {
constexpr int kB = 8, kNG = 5, kNL = 75, kNF = 196, kC = 640;
constexpr int kNTokL = kNL * kNF;      // 14700
constexpr int kNTot = kNG + kNTokL;    // 14705
constexpr float kEps = 1e-12f;
constexpr float kInvAlpha = 10.0f;
constexpr int kKC = 20;                // 640 / 32 K-chunks
constexpr int kTiles = 230;            // 64-token tiles per batch
constexpr int kNT = 5;                 // 16-d tiles per wave (wave = 64 tok x 80 d)
}

typedef __attribute__((ext_vector_type(8))) short short8;
typedef __attribute__((ext_vector_type(4))) short short4v;
typedef __attribute__((ext_vector_type(4))) float floatx4;

union S8U { short8 v; ushort u[8]; };
union S4U { short4v v; ushort u[4]; };

// round-to-nearest-even bf16 split: x ~= hi + lo
__device__ __forceinline__ void bsplit(float x, ushort& h, ushort& l) {
  union { float f; uint u; } a; a.f = x;
  uint uh = (a.u + 0x7FFFu + ((a.u >> 16) & 1u)) >> 16;
  h = (ushort)uh;
  union { uint u; float f; } bb; bb.u = uh << 16;
  float r = x - bb.f;
  union { float f; uint u; } c; c.f = r;
  l = (ushort)((c.u + 0x7FFFu + ((c.u >> 16) & 1u)) >> 16);
}

#define MFMA_BF16(a, b, c) __builtin_amdgcn_mfma_f32_16x16x32_bf16(a, b, c, 0, 0, 0)

// barrier that does NOT drain vmcnt (keeps global prefetches in flight)
__device__ __forceinline__ void bar_lds() {
  asm volatile("s_waitcnt lgkmcnt(0)\n\ts_barrier" ::: "memory");
}

// ---------- small kernels ----------

// s_l[b,c] = sum_t local_f[b,t,c]. grid (8,128), block 320 (float4 per lane).
// 128 slices of 115 rows (h=0: first 58, h=1: last 57) -> 20 waves/CU in flight.
__global__ void k_sum_local(const float* __restrict__ lf, float* __restrict__ s_l) {
  const int b = blockIdx.x, slice = blockIdx.y;
  const int tid = threadIdx.x;
  const int c4 = tid % 160, h = tid / 160;       // column group, row half
  const int t0 = slice * 115 + h * 58;
  const int nrow = min(h ? 57 : 58, kNTokL - t0);
  const float* p = lf + ((size_t)b * kNTokL + t0) * kC + c4 * 4;
  float4 acc = {0.f, 0.f, 0.f, 0.f};
#pragma unroll 2
  for (int i = 0; i < nrow; ++i) {
    const float4 v = *(const float4*)(p + (size_t)i * kC);
    acc.x += v.x; acc.y += v.y; acc.z += v.z; acc.w += v.w;
  }
  float* dst = &s_l[b * kC + c4 * 4];
  atomicAdd(dst + 0, acc.x);
  atomicAdd(dst + 1, acc.y);
  atomicAdd(dst + 2, acc.z);
  atomicAdd(dst + 3, acc.w);
}

// Wk -> Wh/Wl in lane-major MFMA frag tiles, kc-major layout: tile (kc,dt) =
// 512 shorts at (kc*40+dt)*512; lane l (l = quad*16 + n) holds
// W[d = dt*16+n][k = kc*32 + quad*8 .. +8].
__global__ void k_cvtW(const float* __restrict__ Wk, ushort* __restrict__ Wh,
                       ushort* __restrict__ Wl) {
  const int wv = blockIdx.x * 4 + (threadIdx.x >> 6);  // 0..799 = 40 dt x 20 kc
  const int lane = threadIdx.x & 63;
  const int kc = wv % kKC, dt = wv / kKC;
  const int fm = lane & 15, quad = lane >> 4;
  const float* p = Wk + (size_t)(dt * 16 + fm) * kC + kc * 32 + quad * 8;
  float4 a = *(const float4*)p;
  float4 c = *(const float4*)(p + 4);
  S8U h, l;
  bsplit(a.x, h.u[0], l.u[0]); bsplit(a.y, h.u[1], l.u[1]);
  bsplit(a.z, h.u[2], l.u[2]); bsplit(a.w, h.u[3], l.u[3]);
  bsplit(c.x, h.u[4], l.u[4]); bsplit(c.y, h.u[5], l.u[5]);
  bsplit(c.z, h.u[6], l.u[6]); bsplit(c.w, h.u[7], l.u[7]);
  const size_t off = ((size_t)kc * 40 + dt) * 512 + (size_t)lane * 8;
  *(short8*)(Wh + off) = h.v;
  *(short8*)(Wl + off) = l.v;
}

// One wave per (b,d): m[b,d] = (Wq[d]·sum_g gf + Wk[d]·s_l[b]) / 14705
// gc[b,g,d] = Wq[d]·gf[b,g] - m[b,d]
__global__ void k_proj_mean(const float* __restrict__ Wq, const float* __restrict__ Wk,
                            const float* __restrict__ gf, const float* __restrict__ s_l,
                            float* __restrict__ m, float* __restrict__ gc) {
  const int wid = blockIdx.x * 4 + (threadIdx.x >> 6);
  const int lane = threadIdx.x & 63;
  const int b = wid / kC, d = wid % kC;
  float ak = 0.f, ag[kNG] = {0.f, 0.f, 0.f, 0.f, 0.f};
  for (int c = lane; c < kC; c += 64) {
    const float wq = Wq[d * kC + c];
    const float wk = Wk[d * kC + c];
    ak += wk * s_l[b * kC + c];
#pragma unroll
    for (int g = 0; g < kNG; ++g) ag[g] += wq * gf[(b * kNG + g) * kC + c];
  }
#pragma unroll
  for (int off = 32; off > 0; off >>= 1) {
    ak += __shfl_xor(ak, off);
#pragma unroll
    for (int g = 0; g < kNG; ++g) ag[g] += __shfl_xor(ag[g], off);
  }
  if (lane == 0) {
    float aq = 0.f;
#pragma unroll
    for (int g = 0; g < kNG; ++g) aq += ag[g];
    const float mv = (aq + ak) / (float)kNTot;
    m[b * kC + d] = mv;
#pragma unroll
    for (int g = 0; g < kNG; ++g) gc[(b * kNG + g) * kC + d] = ag[g] - mv;
  }
}

__global__ void k_norm_g(const float* __restrict__ gc, float* __restrict__ gn) {
  const int row = blockIdx.x;
  __shared__ float red[256];
  float a = 0.f;
  for (int d = threadIdx.x; d < kC; d += 256) {
    const float v = gc[row * kC + d];
    a += v * v;
  }
  red[threadIdx.x] = a;
  __syncthreads();
  for (int s = 128; s > 0; s >>= 1) {
    if (threadIdx.x < s) red[threadIdx.x] += red[threadIdx.x + s];
    __syncthreads();
  }
  const float rs = 1.0f / sqrtf(red[0] + kEps);
  for (int d = threadIdx.x; d < kC; d += 256) gn[row * kC + d] = gc[row * kC + d] * rs;
}

// ---------- the big fused kernel ----------
// Block = 64 tokens x ALL 640 d. 8 waves, wave wn = 64 tok x 80 d (5 nt tiles).
// K-loop processes 64-k per barrier (2x 32-k sub-chunks per LDS buffer):
// 10 barriers total. A globals prefetched one full iteration (2 chunks) ahead;
// B fragments register-double-buffered per 32-k chunk. MFMA emitted in 3
// passes of 20 independent ops (same per-accumulator order -> bit-identical).
__global__ __launch_bounds__(512, 1) void k_big(
    const float* __restrict__ lf, const ushort* __restrict__ Wh,
    const ushort* __restrict__ Wl, const float* __restrict__ m,
    const float* __restrict__ gn, float* __restrict__ scores) {
  __shared__ char smem[32768];  // buf p @ p*16384: h sub0|h sub1|l sub0|l sub1 (4KB each)
  ushort* A0 = (ushort*)smem;
  ushort* A1 = (ushort*)(smem + 16384);
  float* red = (float*)smem;  // [8 waves][64 rows][6] overlays buf0 in epilogue

  const int tid = threadIdx.x;
  const int wn = tid >> 6, lane = tid & 63;
  const int fm = lane & 15, quad = lane >> 4;
  const int b = blockIdx.x & 7, tile = blockIdx.x >> 3;
  const int tok0 = tile * 64;

  // staging role: token row sr (0..63), float4 col group sq (0..7)
  const int sr = tid >> 3, sq = tid & 7;
  const int st = tok0 + sr;
  const bool sok = st < kNTokL;
  const float* xrow = lf + ((size_t)b * kNTokL + st) * kC + sq * 4;
  // frag-tile offset (shorts) within one 32-k sub-chunk:
  // tile (sr>>4), lane' = (sq>>1)*16 + (sr&15), j = (sq&1)*4
  const int aoff = ((sr >> 4) << 9) + (((sq >> 1) * 16 + (sr & 15)) << 3) + ((sq & 1) << 2);

  floatx4 acc[4][kNT];
#pragma unroll
  for (int i = 0; i < 4; ++i)
#pragma unroll
    for (int j = 0; j < kNT; ++j) acc[i][j] = (floatx4){0.f, 0.f, 0.f, 0.f};

#define STAGE_A(XV, AB, CI)                                   \
  {                                                           \
    S4U _h, _l;                                               \
    bsplit((XV).x, _h.u[0], _l.u[0]);                         \
    bsplit((XV).y, _h.u[1], _l.u[1]);                         \
    bsplit((XV).z, _h.u[2], _l.u[2]);                         \
    bsplit((XV).w, _h.u[3], _l.u[3]);                         \
    *(short4v*)((AB) + (CI) * 2048 + aoff) = _h.v;            \
    *(short4v*)((AB) + 4096 + (CI) * 2048 + aoff) = _l.v;     \
  }

#define LOADB(BH, BL, KCI)                                                        \
  {                                                                               \
    const size_t _o = ((size_t)(KCI) * 40 + wn * 5) * 512 + (size_t)lane * 8;     \
    _Pragma("unroll") for (int nt = 0; nt < kNT; ++nt) {                          \
      BH[nt] = *(const short8*)(Wh + _o + nt * 512);                              \
      BL[nt] = *(const short8*)(Wl + _o + nt * 512);                              \
    }                                                                             \
  }

#define READA(AB, CI)                                                             \
  {                                                                               \
    _Pragma("unroll") for (int mt = 0; mt < 4; ++mt) {                            \
      ah[mt] = *(const short8*)((AB) + (CI) * 2048 + mt * 512 + lane * 8);        \
      al[mt] = *(const short8*)((AB) + 4096 + (CI) * 2048 + mt * 512 + lane * 8); \
    }                                                                             \
  }

#define DOMFMA3(BH, BL)                                                \
  {                                                                    \
    _Pragma("unroll") for (int nt = 0; nt < kNT; ++nt)                 \
        _Pragma("unroll") for (int mt = 0; mt < 4; ++mt)               \
            acc[mt][nt] = MFMA_BF16(ah[mt], BH[nt], acc[mt][nt]);      \
    _Pragma("unroll") for (int nt = 0; nt < kNT; ++nt)                 \
        _Pragma("unroll") for (int mt = 0; mt < 4; ++mt)               \
            acc[mt][nt] = MFMA_BF16(al[mt], BH[nt], acc[mt][nt]);      \
    _Pragma("unroll") for (int nt = 0; nt < kNT; ++nt)                 \
        _Pragma("unroll") for (int mt = 0; mt < 4; ++mt)               \
            acc[mt][nt] = MFMA_BF16(ah[mt], BL[nt], acc[mt][nt]);      \
  }

  const float4 fzero = {0.f, 0.f, 0.f, 0.f};
  // prologue: stage chunks 0,1 into buf0; prefetch chunks 2,3 into regs
  float4 x0 = sok ? *(const float4*)xrow : fzero;
  float4 x1 = sok ? *(const float4*)(xrow + 32) : fzero;
  STAGE_A(x0, A0, 0);
  STAGE_A(x1, A0, 1);
  float4 xA0 = sok ? *(const float4*)(xrow + 64) : fzero;
  float4 xA1 = sok ? *(const float4*)(xrow + 96) : fzero;
  float4 xB0 = fzero, xB1 = fzero;
  short8 BH0[kNT], BL0[kNT], BH1[kNT], BL1[kNT];
  LOADB(BH0, BL0, 0);

  short8 ah[4], al[4];
  ushort* Ac = A0;
  ushort* An = A1;
  for (int kc = 0; kc < kKC; kc += 2) {
    bar_lds();                       // all waves' stages into Ac done; reads of An done
    READA(Ac, 0);
    LOADB(BH1, BL1, kc + 1);         // B for odd sub-chunk (always exists)
    if (sok && kc + 4 < kKC) {       // A globals two chunks (one iter) ahead
      xB0 = *(const float4*)(xrow + (kc + 4) * 32);
      xB1 = *(const float4*)(xrow + (kc + 5) * 32);
    }
    if (kc + 2 < kKC) {              // stage next iteration's chunks into An
      STAGE_A(xA0, An, 0);
      STAGE_A(xA1, An, 1);
    }
    DOMFMA3(BH0, BL0);               // compute sub-chunk kc
    READA(Ac, 1);
    if (kc + 2 < kKC) LOADB(BH0, BL0, kc + 2);  // B for next iter's even sub-chunk
    xA0 = xB0; xA1 = xB1;
    DOMFMA3(BH1, BL1);               // compute sub-chunk kc+1
    ushort* tswap = Ac; Ac = An; An = tswap;
  }

  // ---- epilogue: center, reduce over d, combine 8 waves, write scores ----
  float mv[kNT], gvv[5][kNT];
#pragma unroll
  for (int nt = 0; nt < kNT; ++nt) {
    const int d = wn * 80 + nt * 16 + fm;
    mv[nt] = m[b * kC + d];
#pragma unroll
    for (int g = 0; g < 5; ++g) gvv[g][nt] = gn[(b * kNG + g) * kC + d];
  }

  bar_lds();  // all waves' K-loop ds_reads done before red[] overwrites bufs
#pragma unroll
  for (int mt = 0; mt < 4; ++mt)
#pragma unroll
    for (int reg = 0; reg < 4; ++reg) {
      float part[6] = {0.f, 0.f, 0.f, 0.f, 0.f, 0.f};
#pragma unroll
      for (int nt = 0; nt < kNT; ++nt) {
        const float yc = acc[mt][nt][reg] - mv[nt];
        part[0] += yc * yc;
#pragma unroll
        for (int g = 0; g < 5; ++g) part[1 + g] += yc * gvv[g][nt];
      }
#pragma unroll
      for (int off = 1; off < 16; off <<= 1)
#pragma unroll
        for (int v = 0; v < 6; ++v) part[v] += __shfl_xor(part[v], off);
      if (fm == 0) {
        const int row = mt * 16 + quad * 4 + reg;
#pragma unroll
        for (int v = 0; v < 6; ++v) red[((size_t)wn * 64 + row) * 6 + v] = part[v];
      }
    }
  bar_lds();
  if (tid < 64) {
    const int tok = tok0 + tid;
    if (tok < kNTokL) {
      float s[6] = {0.f, 0.f, 0.f, 0.f, 0.f, 0.f};
#pragma unroll
      for (int w = 0; w < 8; ++w)
#pragma unroll
        for (int v = 0; v < 6; ++v) s[v] += red[((size_t)w * 64 + tid) * 6 + v];
      const float rs = (1.0f / sqrtf(s[0] + kEps)) * kInvAlpha;
      const size_t t = (size_t)b * kNTokL + tok;
#pragma unroll
      for (int g = 0; g < 5; ++g)
        scores[(size_t)g * (kB * kNTokL) + t] = s[1 + g] * rs;
    }
  }
#undef STAGE_A
#undef LOADB
#undef READA
#undef DOMFMA3
}

// softmax over f (196) per (b,l,g) row; one wave per row. scores pre-scaled.
__global__ void k_softmax(const float* __restrict__ scores, float* __restrict__ out) {
  const int wid = blockIdx.x * 4 + (threadIdx.x >> 6);
  const int lane = threadIdx.x & 63;
  const int b = wid / (kNL * kNG);
  const int rem = wid % (kNL * kNG);
  const int l = rem / kNG, g = rem % kNG;
  float sv[4];
  float mx = -1e30f;
#pragma unroll
  for (int u = 0; u < 4; ++u) {
    const int f = lane + 64 * u;
    if (f < kNF) {
      const size_t t = (size_t)b * kNTokL + (size_t)l * kNF + f;
      sv[u] = scores[(size_t)g * (kB * kNTokL) + t];
      mx = fmaxf(mx, sv[u]);
    } else {
      sv[u] = 0.f;
    }
  }
#pragma unroll
  for (int off = 32; off > 0; off >>= 1) mx = fmaxf(mx, __shfl_xor(mx, off));
  float se = 0.f;
#pragma unroll
  for (int u = 0; u < 4; ++u) {
    const int f = lane + 64 * u;
    const float e = (f < kNF) ? expf(sv[u] - mx) : 0.f;
    sv[u] = e;
    se += e;
  }
#pragma unroll
  for (int off = 32; off > 0; off >>= 1) se += __shfl_xor(se, off);
  const float inv = 1.0f / se;
#pragma unroll
  for (int u = 0; u < 4; ++u) {
    const int f = lane + 64 * u;
    if (f < kNF) out[((size_t)(b * kNL + l) * kNG + g) * kNF + f] = sv[u] * inv;
  }
}

// ===================== launcher =====================

extern "C" void kernel_launch(void* const* d_in, const int* in_sizes, int n_in,
                              void* d_out, int out_size, void* d_ws, size_t ws_size,
                              hipStream_t stream) {
  (void)in_sizes; (void)n_in; (void)out_size; (void)ws_size;
  const float* gf = (const float*)d_in[0];  // [8,5,640]
  const float* lf = (const float*)d_in[1];  // [8,75,196,640]
  const float* Wq = (const float*)d_in[2];  // [640,640]
  const float* Wk = (const float*)d_in[3];  // [640,640]
  float* ws = (float*)d_ws;
  float* out = (float*)d_out;

  // workspace (float offsets): total ~4.2 MB
  float* s_l    = ws;            // 5120
  float* m      = ws + 5120;     // 5120
  float* gc     = ws + 10240;    // 25600
  float* gn     = ws + 35840;    // 25600
  float* scores = ws + 61440;    // 5*117600 = 588000  (layout [g][t])
  ushort* Wh    = (ushort*)(ws + 649440);  // 409600 shorts
  ushort* Wl    = (ushort*)(ws + 854240);  // 409600 shorts

  hipMemsetAsync(s_l, 0, (size_t)5120 * 4, stream);

  k_sum_local<<<dim3(kB, 128), 320, 0, stream>>>(lf, s_l);
  k_cvtW<<<200, 256, 0, stream>>>(Wk, Wh, Wl);
  k_proj_mean<<<(kB * kC) / 4, 256, 0, stream>>>(Wq, Wk, gf, s_l, m, gc);
  k_norm_g<<<kB * kNG, 256, 0, stream>>>(gc, gn);
  k_big<<<kTiles * kB, 512, 0, stream>>>(lf, Wh, Wl, m, gn, scores);
  k_softmax<<<750, 256, 0, stream>>>(scores, out);
}